// Round 11
// baseline (4155.417 us; speedup 1.0000x reference)
//
#include <hip/hip_runtime.h>
#include <hip/hip_fp16.h>

#define T_ 1000

typedef float v2f __attribute__((ext_vector_type(2)));

__device__ __forceinline__ float sigf(float x) { return 1.0f / (1.0f + __expf(-x)); }
__device__ __forceinline__ float tanh_fast(float x) { return 1.0f - 2.0f / (1.0f + __expf(2.0f * x)); }
__device__ __forceinline__ float dot4(float4 a, float4 b) {
  return a.x * b.x + a.y * b.y + a.z * b.z + a.w * b.w;
}
__device__ __forceinline__ void pkfma(v2f& acc, float4 w, float4 v) {
  v2f wl; wl[0] = w.x; wl[1] = w.y;
  v2f wh; wh[0] = w.z; wh[1] = w.w;
  v2f vl; vl[0] = v.x; vl[1] = v.y;
  v2f vh; vh[0] = v.z; vh[1] = v.w;
  acc += wl * vl;
  acc += wh * vh;
}
__device__ __forceinline__ unsigned short f2bf(float f) {
  unsigned u = __float_as_uint(f);
  u = (u + 0x7fffu + ((u >> 16) & 1u)) >> 16;  // RNE
  return (unsigned short)u;
}
__device__ __forceinline__ float bf2f(unsigned short h) {
  return __uint_as_float(((unsigned)h) << 16);
}
__device__ __forceinline__ float4 bf4_to_f4(ushort4 u) {
  float4 r;
  r.x = bf2f(u.x); r.y = bf2f(u.y); r.z = bf2f(u.z); r.w = bf2f(u.w);
  return r;
}

__global__ void bail_kernel(float* out, int n) {
  for (int i = threadIdx.x; i < n; i += 256) out[i] = 0.0f;
}

// ---------------- LN stats: per row (mu, rs) ----------------
__global__ __launch_bounds__(256) void ln_stats_kernel(const float* __restrict__ x,
                                                       float* __restrict__ mu_arr,
                                                       float* __restrict__ rs_arr) {
  const int lane = threadIdx.x & 63;
  const int w = threadIdx.x >> 6;
  const long row = (long)blockIdx.x * 4 + w;
  float v = (lane < 40) ? x[row * 40 + lane] : 0.0f;
  float s1 = v, s2 = v * v;
  for (int m = 32; m; m >>= 1) {
    s1 += __shfl_xor(s1, m, 64);
    s2 += __shfl_xor(s2, m, 64);
  }
  if (lane == 0) {
    const float mu = s1 * (1.0f / 40.0f);
    const float var = s2 * (1.0f / 40.0f) - mu * mu;
    mu_arr[row] = mu;
    rs_arr[row] = rsqrtf(var + 1e-5f);
  }
}

// ---------------- xw0 chunk = LN(x)[slice] @ Wih0^T  (LN fused into A-load) ----------------
__global__ __launch_bounds__(256, 2) void gemm_xw0(
    const float* __restrict__ x,
    const float* __restrict__ mu_arr, const float* __restrict__ rs_arr,
    const float* __restrict__ ln_g, const float* __restrict__ ln_b,
    const float* __restrict__ Wf, const float* __restrict__ Wb,
    float* __restrict__ xwf, float* __restrict__ xwb,
    int Tc, int t0f, int t0b) {
  __shared__ float As[64 * 44];   // 64 rows x 11 float4 (10 data + 1 pad)
  __shared__ float Bs[128 * 44];
  const int tid = threadIdx.x;
  const int tx = tid & 15, ty = tid >> 4;
  const int r0 = blockIdx.x * 64;
  const int jt = blockIdx.y;
  const int dir = jt >> 2, nh = jt & 3;
  const float* __restrict__ W = dir ? Wb : Wf;
  float* __restrict__ out = dir ? xwb : xwf;
  const int jbase = nh * 128;
  const int t0 = dir ? t0b : t0f;

  float4* As4 = (float4*)As;
  float4* Bs4 = (float4*)Bs;
  {  // A stage with fused LayerNorm: 4 threads per row
    const int row = tid >> 2;
    const int t4 = tid & 3;
    const int r = r0 + row;
    const int br = r / Tc;
    const long xrow = (long)br * T_ + t0 + (r - br * Tc);
    const float mu = mu_arr[xrow];
    const float rs = rs_arr[xrow];
#pragma unroll
    for (int m = 0; m < 3; ++m) {
      const int k4 = t4 + m * 4;  // 0..11; data cols 0..9 (pad col 10 never read)
      if (k4 < 10) {
        const float4 v = *(const float4*)&x[xrow * 40 + k4 * 4];
        const float4 g4 = *(const float4*)&ln_g[k4 * 4];
        const float4 b4 = *(const float4*)&ln_b[k4 * 4];
        float4 xn;
        xn.x = (v.x - mu) * rs * g4.x + b4.x;
        xn.y = (v.y - mu) * rs * g4.y + b4.y;
        xn.z = (v.z - mu) * rs * g4.z + b4.z;
        xn.w = (v.w - mu) * rs * g4.w + b4.w;
        As4[row * 11 + k4] = xn;
      }
    }
  }
  {  // B stage: 2 threads per row
    const int row = tid & 127;
    const int h = tid >> 7;
#pragma unroll
    for (int m = 0; m < 5; ++m) {
      const int k4 = h + m * 2;  // 0..9
      Bs4[row * 11 + k4] = *(const float4*)&W[(long)(jbase + row) * 40 + k4 * 4];
    }
  }
  __syncthreads();

  v2f acc2[4][8];
#pragma unroll
  for (int r = 0; r < 4; ++r)
#pragma unroll
    for (int c2 = 0; c2 < 8; ++c2) acc2[r][c2] = 0.0f;
#pragma unroll 1
  for (int k4 = 0; k4 < 10; ++k4) {
    float4 av[4];
#pragma unroll
    for (int r = 0; r < 4; ++r) av[r] = As4[(ty * 4 + r) * 11 + k4];
#pragma unroll
    for (int c2 = 0; c2 < 8; ++c2) {
      const float4 bv = Bs4[(tx + 16 * c2) * 11 + k4];
#pragma unroll
      for (int r = 0; r < 4; ++r) pkfma(acc2[r][c2], av[r], bv);
    }
  }
#pragma unroll
  for (int r = 0; r < 4; ++r) {
    const long ob = (long)(r0 + ty * 4 + r) * 512 + jbase + tx;
#pragma unroll
    for (int c2 = 0; c2 < 8; ++c2) out[ob + c2 * 16] = acc2[r][c2][0] + acc2[r][c2][1];
  }
}

// ---------------- Unified recurrence (both layers), time-chunked ----------------
// lane: unit u = wave*16 + (lane>>2), k-quarter p = lane&3. Hybrid weight storage:
// gates i,g in REGISTERS f32 (64 floats/lane -> fits the hard 128-VGPR cap of
// 512-thread blocks, so no AGPR spill movs -- rounds 7-10's 2.5x VALU inflation);
// gates f,o in LDS as f16 (64KB, 16B units XOR-swizzled by unit&7 -> <=2-way banks),
// streamed each step. Input term xw precomputed by gemm_xw0/gemm_xw1.
// h4f parity double-buffer: read su&1, write (su&1)^1; 1 barrier/step.
__global__ __launch_bounds__(512) void rec_fused(
    const float* __restrict__ xw_f, const float* __restrict__ xw_b,
    const float* __restrict__ Whh_f, const float* __restrict__ Whh_b,
    const float* __restrict__ bih_f, const float* __restrict__ bhh_f,
    const float* __restrict__ bih_b, const float* __restrict__ bhh_b,
    float* __restrict__ h0out, unsigned short* __restrict__ h1out, int out_bf16,
    float* __restrict__ state, int Tc, int t0f, int t0b, int first) {
  const int tid = threadIdx.x;
  const int u = (tid >> 6) * 16 + ((tid & 63) >> 2);
  const int p = tid & 3;
  const int brow = blockIdx.x & 127;
  const int dir = blockIdx.x >> 7;
  const float* __restrict__ xw  = dir ? xw_b : xw_f;
  const float* __restrict__ Whh = dir ? Whh_b : Whh_f;
  const float* __restrict__ bih = dir ? bih_b : bih_f;
  const float* __restrict__ bhh = dir ? bhh_b : bhh_f;
  const int t0 = dir ? t0b : t0f;

  __shared__ __align__(16) unsigned short wl[2 * 128 * 128];  // f16 gates f,o
  __shared__ float h4f[2][128];
  __shared__ float hring[2][8][128];

  // ---- stage f,o gate weights into LDS as f16, swizzled 16B units ----
#pragma unroll
  for (int k2 = 0; k2 < 8; ++k2) {
    const int U = tid + k2 * 512;  // 16B-unit index 0..4095
    const int g2 = U >> 11;
    const int uu = (U >> 4) & 127;
    const int j  = U & 15;
    const int grow = (g2 ? 384 : 128) + uu;
    const float4 va = *(const float4*)&Whh[grow * 128 + j * 8];
    const float4 vb = *(const float4*)&Whh[grow * 128 + j * 8 + 4];
    const int js = j ^ (uu & 7);
    __half2* dst = (__half2*)&wl[((g2 * 128 + uu) * 16 + js) * 8];
    dst[0] = __floats2half2_rn(va.x, va.y);
    dst[1] = __floats2half2_rn(va.z, va.w);
    dst[2] = __floats2half2_rn(vb.x, vb.y);
    dst[3] = __floats2half2_rn(vb.z, vb.w);
  }

  // ---- register weights: gate i (rows 0..127) and g (rows 256..383), chunk-rotated ----
  float4 whr[2][8];
  {
    const float4* wi_ = (const float4*)(Whh + u * 128 + p * 32);
    const float4* wg_ = (const float4*)(Whh + (256 + u) * 128 + p * 32);
#pragma unroll
    for (int ff2 = 0; ff2 < 4; ++ff2) {
      const int c4 = (ff2 + p) & 3;
      whr[0][2 * ff2]     = wi_[2 * c4];
      whr[0][2 * ff2 + 1] = wi_[2 * c4 + 1];
      whr[1][2 * ff2]     = wg_[2 * c4];
      whr[1][2 * ff2 + 1] = wg_[2 * c4 + 1];
    }
  }
  const int myrow = p * 128 + u;
  const float bias_p = bih[myrow] + bhh[myrow];

  float* sblk = state + (long)blockIdx.x * 256;
  float c = 0.0f;
  if (first) {
    if (tid < 128) h4f[0][tid] = 0.0f;
  } else {
    if (tid < 128) h4f[0][tid] = sblk[tid];
    c = sblk[128 + u];  // replicated per quad
  }
  const long gbase = (long)brow * Tc;
  float xr[8];
#pragma unroll
  for (int v = 0; v < 8; ++v) {
    xr[v] = 0.0f;
    if (v < Tc) {
      const int tr = dir ? (Tc - 1 - v) : v;
      xr[v] = xw[(gbase + tr) * 512 + myrow];
    }
  }
  __syncthreads();

  const int nSB = (Tc + 7) / 8;
  const long obase = (long)brow * T_;
  for (int sb = 0; sb < nSB; ++sb) {
    const int rb = sb & 1;
#pragma unroll
    for (int su = 0; su < 8; ++su) {
      const int s = sb * 8 + su;
      if (s >= Tc) break;  // uniform
      const int rdq = su & 1, wrq = rdq ^ 1;
      if (su == 0 && sb > 0) {  // bulk store of previous (full) group
#pragma unroll
        for (int e = 0; e < 2; ++e) {
          const int idx = tid + e * 512;
          const int v = idx >> 7, j = idx & 127;
          const int s2 = (sb - 1) * 8 + v;
          const int tt = dir ? (Tc - 1 - s2) : s2;
          const long oidx = (obase + (t0 + tt)) * 256 + dir * 128 + j;
          const float hval = hring[rb ^ 1][v][j];
          if (out_bf16) h1out[oidx] = f2bf(hval);
          else          h0out[oidx] = hval;
        }
      }
      // ---- dot phase ----
      float ai = 0.f, af = 0.f, ag = 0.f, ao = 0.f;
      const float4* h4v = (const float4*)h4f[rdq];
#pragma unroll
      for (int ff2 = 0; ff2 < 4; ++ff2) {
        const int c4 = (ff2 + p) & 3;
        const float4 hva = h4v[p * 8 + 2 * c4];
        const float4 hvb = h4v[p * 8 + 2 * c4 + 1];
        ai += dot4(hva, whr[0][2 * ff2]) + dot4(hvb, whr[0][2 * ff2 + 1]);
        ag += dot4(hva, whr[1][2 * ff2]) + dot4(hvb, whr[1][2 * ff2 + 1]);
        const int js = (p * 4 + c4) ^ (u & 7);
        const float4 wfv = *(const float4*)&wl[(u * 16 + js) * 8];
        const float4 wov = *(const float4*)&wl[((128 + u) * 16 + js) * 8];
        const __half2* hf2 = (const __half2*)&wfv;
        const __half2* ho2 = (const __half2*)&wov;
        float2 t;
        t = __half22float2(hf2[0]); af += t.x * hva.x + t.y * hva.y;
        t = __half22float2(hf2[1]); af += t.x * hva.z + t.y * hva.w;
        t = __half22float2(hf2[2]); af += t.x * hvb.x + t.y * hvb.y;
        t = __half22float2(hf2[3]); af += t.x * hvb.z + t.y * hvb.w;
        t = __half22float2(ho2[0]); ao += t.x * hva.x + t.y * hva.y;
        t = __half22float2(ho2[1]); ao += t.x * hva.z + t.y * hva.w;
        t = __half22float2(ho2[2]); ao += t.x * hvb.x + t.y * hvb.y;
        t = __half22float2(ho2[3]); ao += t.x * hvb.z + t.y * hvb.w;
      }
      const float xin = xr[su] + bias_p;
      float pg0 = ai + ((p == 0) ? xin : 0.0f);
      float pg1 = af + ((p == 1) ? xin : 0.0f);
      float pg2 = ag + ((p == 2) ? xin : 0.0f);
      float pg3 = ao + ((p == 3) ? xin : 0.0f);
      pg0 += __shfl_xor(pg0, 1, 64); pg0 += __shfl_xor(pg0, 2, 64);
      pg1 += __shfl_xor(pg1, 1, 64); pg1 += __shfl_xor(pg1, 2, 64);
      pg2 += __shfl_xor(pg2, 1, 64); pg2 += __shfl_xor(pg2, 2, 64);
      pg3 += __shfl_xor(pg3, 1, 64); pg3 += __shfl_xor(pg3, 2, 64);
      const float ig = sigf(pg0);
      const float fg = sigf(pg1);
      const float gg = tanh_fast(pg2);
      const float og = sigf(pg3);
      c = fg * c + ig * gg;
      const float hv = og * tanh_fast(c);
      if (p == 0) { h4f[wrq][u] = hv; hring[rb][su][u] = hv; }
      if (su == 7) {  // refill xw for next group
#pragma unroll
        for (int v = 0; v < 8; ++v) {
          const int sn = s + 1 + v;
          xr[v] = 0.0f;
          if (sn < Tc) {
            const int tr = dir ? (Tc - 1 - sn) : sn;
            xr[v] = xw[(gbase + tr) * 512 + myrow];
          }
        }
      }
      __syncthreads();
    }
  }
  {  // final (possibly partial) group store
    const int sbL = (Tc - 1) >> 3;
    const int cnt = Tc - sbL * 8;
    const int rbL = sbL & 1;
#pragma unroll
    for (int e = 0; e < 2; ++e) {
      const int idx = tid + e * 512;
      const int v = idx >> 7, j = idx & 127;
      if (v < cnt) {
        const int s2 = sbL * 8 + v;
        const int tt = dir ? (Tc - 1 - s2) : s2;
        const long oidx = (obase + (t0 + tt)) * 256 + dir * 128 + j;
        const float hval = hring[rbL][v][j];
        if (out_bf16) h1out[oidx] = f2bf(hval);
        else          h0out[oidx] = hval;
      }
    }
  }
  if (tid < 128) sblk[tid] = h4f[Tc & 1][tid];
  if (p == 0) sblk[128 + u] = c;
}

// ---------------- xw1 chunk GEMM: tile M=64 x N=128, K=256, micro 4x8, pk acc ----------------
__global__ __launch_bounds__(256, 2) void gemm_xw1(
    const float* __restrict__ h0,
    const float* __restrict__ Wf, const float* __restrict__ Wb,
    float* __restrict__ xwf, float* __restrict__ xwb,
    int Tc, int t0f, int t0b) {
  __shared__ float As[64 * 36];
  __shared__ float Bs[128 * 36];
  __shared__ int rowbase[64];
  const int tid = threadIdx.x;
  const int tx = tid & 15, ty = tid >> 4;
  const int r0 = blockIdx.x * 64;
  const int jt = blockIdx.y;
  const int dir = jt >> 2;
  const int nh = jt & 3;
  const float* __restrict__ W = dir ? Wb : Wf;
  float* __restrict__ out = dir ? xwb : xwf;
  const int jbase = nh * 128;
  const int t0 = dir ? t0b : t0f;

  if (tid < 64) {
    const int r = r0 + tid;
    const int br = r / Tc;
    rowbase[tid] = br * T_ + t0 + (r - br * Tc);
  }

  float4* As4 = (float4*)As;
  float4* Bs4 = (float4*)Bs;
  v2f acc2[4][8];
#pragma unroll
  for (int r = 0; r < 4; ++r)
#pragma unroll
    for (int c2 = 0; c2 < 8; ++c2) acc2[r][c2] = 0.0f;
#pragma unroll 1
  for (int kk = 0; kk < 8; ++kk) {
    __syncthreads();
#pragma unroll
    for (int i = 0; i < 2; ++i) {
      const int q = tid + i * 256;
      const int row = q >> 3, k4 = q & 7;
      As4[row * 9 + k4] = *(const float4*)&h0[(long)rowbase[row] * 256 + kk * 32 + k4 * 4];
    }
#pragma unroll
    for (int i = 0; i < 4; ++i) {
      const int q = tid + i * 256;
      const int row = q >> 3, k4 = q & 7;
      Bs4[row * 9 + k4] = *(const float4*)&W[(long)(jbase + row) * 256 + kk * 32 + k4 * 4];
    }
    __syncthreads();
#pragma unroll 1
    for (int k4 = 0; k4 < 8; ++k4) {
      float4 av[4];
#pragma unroll
      for (int r = 0; r < 4; ++r) av[r] = As4[(ty * 4 + r) * 9 + k4];
#pragma unroll
      for (int c2 = 0; c2 < 8; ++c2) {
        const float4 bv = Bs4[(tx + 16 * c2) * 9 + k4];
#pragma unroll
        for (int r = 0; r < 4; ++r) pkfma(acc2[r][c2], av[r], bv);
      }
    }
  }
#pragma unroll
  for (int r = 0; r < 4; ++r) {
    const long ob = (long)(r0 + ty * 4 + r) * 512 + jbase + tx;
#pragma unroll
    for (int c2 = 0; c2 < 8; ++c2) out[ob + c2 * 16] = acc2[r][c2][0] + acc2[r][c2][1];
  }
}

// ---------------- attention scores ----------------
__global__ __launch_bounds__(256, 2) void score_kernel(
    const unsigned short* __restrict__ h1b, const float* __restrict__ W1,
    const float* __restrict__ b1, const float* __restrict__ w2,
    float* __restrict__ scores) {
  __shared__ float As[64 * 36];
  __shared__ float Bs[128 * 36];
  const int tid = threadIdx.x;
  const int tx = tid & 15, ty = tid >> 4;
  const long r0 = (long)blockIdx.x * 64;

  float4* As4 = (float4*)As;
  float4* Bs4 = (float4*)Bs;
  v2f acc2[4][8];
#pragma unroll
  for (int r = 0; r < 4; ++r)
#pragma unroll
    for (int c2 = 0; c2 < 8; ++c2) acc2[r][c2] = 0.0f;
#pragma unroll 1
  for (int kk = 0; kk < 8; ++kk) {
    __syncthreads();
#pragma unroll
    for (int i = 0; i < 2; ++i) {
      const int q = tid + i * 256;
      const int row = q >> 3, k4 = q & 7;
      const ushort4 uv = *(const ushort4*)&h1b[(r0 + row) * 256 + kk * 32 + k4 * 4];
      As4[row * 9 + k4] = bf4_to_f4(uv);
    }
#pragma unroll
    for (int i = 0; i < 4; ++i) {
      const int q = tid + i * 256;
      const int row = q >> 3, k4 = q & 7;
      Bs4[row * 9 + k4] = *(const float4*)&W1[(long)row * 256 + kk * 32 + k4 * 4];
    }
    __syncthreads();
#pragma unroll 1
    for (int k4 = 0; k4 < 8; ++k4) {
      float4 av[4];
#pragma unroll
      for (int r = 0; r < 4; ++r) av[r] = As4[(ty * 4 + r) * 9 + k4];
#pragma unroll
      for (int c2 = 0; c2 < 8; ++c2) {
        const float4 bv = Bs4[(tx + 16 * c2) * 9 + k4];
#pragma unroll
        for (int r = 0; r < 4; ++r) pkfma(acc2[r][c2], av[r], bv);
      }
    }
  }
#pragma unroll
  for (int r = 0; r < 4; ++r) {
    float s = 0.0f;
#pragma unroll
    for (int c2 = 0; c2 < 8; ++c2) {
      const int col = tx + 16 * c2;
      s += tanh_fast(acc2[r][c2][0] + acc2[r][c2][1] + b1[col]) * w2[col];
    }
#pragma unroll
    for (int m = 1; m < 16; m <<= 1) s += __shfl_xor(s, m, 16);
    if (tx == 0) scores[r0 + ty * 4 + r] = s;
  }
}

// ---------------- softmax over T + ctx + MLP head ----------------
__global__ __launch_bounds__(256, 2) void head_kernel(
    const float* __restrict__ scores, const unsigned short* __restrict__ h1b,
    const float* __restrict__ fW1, const float* __restrict__ fb1,
    const float* __restrict__ fW2, const float* __restrict__ fb2,
    float* __restrict__ outp) {
  const int b = blockIdx.x, tid = threadIdx.x;
  __shared__ float wls[1000];
  __shared__ float red[8];
  __shared__ __align__(16) float ctx[256];
  __shared__ __align__(16) float hid[128];

  float sv[4];
  float mx = -1e30f;
#pragma unroll
  for (int i = 0; i < 4; ++i) {
    const int t = tid + i * 256;
    sv[i] = (t < 1000) ? scores[b * 1000 + t] : -1e30f;
    mx = fmaxf(mx, sv[i]);
  }
  for (int m = 32; m; m >>= 1) mx = fmaxf(mx, __shfl_xor(mx, m, 64));
  if ((tid & 63) == 0) red[tid >> 6] = mx;
  __syncthreads();
  mx = fmaxf(fmaxf(red[0], red[1]), fmaxf(red[2], red[3]));
  float se = 0.0f;
#pragma unroll
  for (int i = 0; i < 4; ++i) {
    const int t = tid + i * 256;
    if (t < 1000) {
      const float e = __expf(sv[i] - mx);
      wls[t] = e;
      se += e;
    }
  }
  for (int m = 32; m; m >>= 1) se += __shfl_xor(se, m, 64);
  if ((tid & 63) == 0) red[4 + (tid >> 6)] = se;
  __syncthreads();
  const float rinv = 1.0f / (red[4] + red[5] + red[6] + red[7]);

  float a = 0.0f;
  const unsigned short* hb = h1b + (long)b * T_ * 256 + tid;
  for (int t = 0; t < T_; ++t) a = fmaf(wls[t], bf2f(hb[t * 256]), a);
  ctx[tid] = a * rinv;
  __syncthreads();
  if (tid < 128) {
    float s = fb1[tid];
    const float4* wr = (const float4*)&fW1[tid * 256];
    const float4* cc = (const float4*)ctx;
#pragma unroll
    for (int f = 0; f < 64; ++f) s += dot4(wr[f], cc[f]);
    hid[tid] = fmaxf(s, 0.0f);
  }
  __syncthreads();
  if (tid < 8) {
    float s = fb2[tid];
    const float4* wr = (const float4*)&fW2[tid * 128];
    const float4* hh = (const float4*)hid;
#pragma unroll
    for (int f = 0; f < 32; ++f) s += dot4(wr[f], hh[f]);
    outp[b * 8 + tid] = s;
  }
}

extern "C" void kernel_launch(void* const* d_in, const int* in_sizes, int n_in,
                              void* d_out, int out_size, void* d_ws, size_t ws_size,
                              hipStream_t stream) {
  (void)in_sizes; (void)n_in; (void)out_size;
  const float* x       = (const float*)d_in[0];
  const float* ln_g    = (const float*)d_in[1];
  const float* ln_b    = (const float*)d_in[2];
  const float* Wih_f0  = (const float*)d_in[3];
  const float* Whh_f0  = (const float*)d_in[4];
  const float* bih_f0  = (const float*)d_in[5];
  const float* bhh_f0  = (const float*)d_in[6];
  const float* Wih_b0  = (const float*)d_in[7];
  const float* Whh_b0  = (const float*)d_in[8];
  const float* bih_b0  = (const float*)d_in[9];
  const float* bhh_b0  = (const float*)d_in[10];
  const float* Wih_f1  = (const float*)d_in[11];
  const float* Whh_f1  = (const float*)d_in[12];
  const float* bih_f1  = (const float*)d_in[13];
  const float* bhh_f1  = (const float*)d_in[14];
  const float* Wih_b1  = (const float*)d_in[15];
  const float* Whh_b1  = (const float*)d_in[16];
  const float* bih_b1  = (const float*)d_in[17];
  const float* bhh_b1  = (const float*)d_in[18];
  const float* attn_W1 = (const float*)d_in[19];
  const float* attn_b1 = (const float*)d_in[20];
  const float* attn_w2 = (const float*)d_in[21];
  const float* fc_W1   = (const float*)d_in[22];
  const float* fc_b1   = (const float*)d_in[23];
  const float* fc_W2   = (const float*)d_in[24];
  const float* fc_b2   = (const float*)d_in[25];

  char* base = (char*)d_ws;
  size_t off = 0;
  auto alloc = [&](size_t bytes) {
    char* ptr = base + off;
    off += (bytes + 255) & ~(size_t)255;
    return ptr;
  };
  float*          h0    = (float*)alloc(32768000ull * 4);          // 131.1 MB
  unsigned short* h1b   = (unsigned short*)alloc(32768000ull * 2); //  65.5 MB
  float*          state = (float*)alloc(65536ull * 4);
  float*          scor  = (float*)alloc(128000ull * 4);
  float*          mu_a  = (float*)alloc(128000ull * 4);
  float*          rs_a  = (float*)alloc(128000ull * 4);

  const size_t rem = (ws_size > off) ? (ws_size - off) : 0;
  static const int cands[16] = {1000, 500, 250, 200, 125, 100, 50, 40, 25, 20, 10, 8, 5, 4, 2, 1};
  int Tc = 0;
  for (int ci = 0; ci < 16; ++ci) {
    if (524288ull * (size_t)cands[ci] <= rem) { Tc = cands[ci]; break; }
  }
  if (Tc == 0) {
    bail_kernel<<<dim3(1), dim3(256), 0, stream>>>((float*)d_out, 1024);
    return;
  }
  float* xwf = (float*)(base + off);
  float* xwb = xwf + 65536L * Tc;

  ln_stats_kernel<<<dim3(32000), dim3(256), 0, stream>>>(x, mu_a, rs_a);
  const int nch = T_ / Tc;
  // Layer 0: xw0 chunk GEMM (LN fused) + recurrence
  for (int ch = 0; ch < nch; ++ch) {
    const int t0f = ch * Tc;
    const int t0b = T_ - (ch + 1) * Tc;
    gemm_xw0<<<dim3(2 * Tc, 8), dim3(256), 0, stream>>>(x, mu_a, rs_a, ln_g, ln_b,
                                                        Wih_f0, Wih_b0, xwf, xwb, Tc, t0f, t0b);
    rec_fused<<<dim3(256), dim3(512), 0, stream>>>(xwf, xwb, Whh_f0, Whh_b0,
                                                   bih_f0, bhh_f0, bih_b0, bhh_b0,
                                                   h0, h1b, 0, state, Tc, t0f, t0b,
                                                   (ch == 0) ? 1 : 0);
  }
  // Layer 1: xw1 chunk GEMM + recurrence (bf16 h1 out)
  for (int ch = 0; ch < nch; ++ch) {
    const int t0f = ch * Tc;
    const int t0b = T_ - (ch + 1) * Tc;
    gemm_xw1<<<dim3(2 * Tc, 8), dim3(256), 0, stream>>>(h0, Wih_f1, Wih_b1, xwf, xwb, Tc, t0f, t0b);
    rec_fused<<<dim3(256), dim3(512), 0, stream>>>(xwf, xwb, Whh_f1, Whh_b1,
                                                   bih_f1, bhh_f1, bih_b1, bhh_b1,
                                                   h0, h1b, 1, state, Tc, t0f, t0b,
                                                   (ch == 0) ? 1 : 0);
  }
  score_kernel<<<dim3(2000), dim3(256), 0, stream>>>(h1b, attn_W1, attn_b1, attn_w2, scor);
  head_kernel<<<dim3(128), dim3(256), 0, stream>>>(scor, h1b, fc_W1, fc_b1, fc_W2, fc_b2,
                                                   (float*)d_out);
}

// Round 13
// 3219.827 us; speedup vs baseline: 1.2906x; 1.2906x over previous
//
#include <hip/hip_runtime.h>
#include <hip/hip_fp16.h>

#define T_ 1000

typedef float v2f __attribute__((ext_vector_type(2)));
typedef __fp16 h2t __attribute__((ext_vector_type(2)));  // matches cvt_pkrtz/fdot2 builtin type

#if defined(__has_builtin)
#if __has_builtin(__builtin_amdgcn_fdot2)
#define HAS_FDOT2 1
#endif
#endif
#ifndef HAS_FDOT2
#define HAS_FDOT2 0
#endif

__device__ __forceinline__ float sigf(float x) { return 1.0f / (1.0f + __expf(-x)); }
__device__ __forceinline__ float tanh_fast(float x) { return 1.0f - 2.0f / (1.0f + __expf(2.0f * x)); }
__device__ __forceinline__ float dot4(float4 a, float4 b) {
  return a.x * b.x + a.y * b.y + a.z * b.z + a.w * b.w;
}
__device__ __forceinline__ void pkfma(v2f& acc, float4 w, float4 v) {
  v2f wl; wl[0] = w.x; wl[1] = w.y;
  v2f wh; wh[0] = w.z; wh[1] = w.w;
  v2f vl; vl[0] = v.x; vl[1] = v.y;
  v2f vh; vh[0] = v.z; vh[1] = v.w;
  acc += wl * vl;
  acc += wh * vh;
}
__device__ __forceinline__ unsigned short f2bf(float f) {
  unsigned u = __float_as_uint(f);
  u = (u + 0x7fffu + ((u >> 16) & 1u)) >> 16;  // RNE
  return (unsigned short)u;
}
__device__ __forceinline__ float bf2f(unsigned short h) {
  return __uint_as_float(((unsigned)h) << 16);
}
__device__ __forceinline__ float4 bf4_to_f4(ushort4 u) {
  float4 r;
  r.x = bf2f(u.x); r.y = bf2f(u.y); r.z = bf2f(u.z); r.w = bf2f(u.w);
  return r;
}

__global__ void bail_kernel(float* out, int n) {
  for (int i = threadIdx.x; i < n; i += 256) out[i] = 0.0f;
}

// ---------------- LN stats: per row (mu, rs) ----------------
__global__ __launch_bounds__(256) void ln_stats_kernel(const float* __restrict__ x,
                                                       float* __restrict__ mu_arr,
                                                       float* __restrict__ rs_arr) {
  const int lane = threadIdx.x & 63;
  const int w = threadIdx.x >> 6;
  const long row = (long)blockIdx.x * 4 + w;
  float v = (lane < 40) ? x[row * 40 + lane] : 0.0f;
  float s1 = v, s2 = v * v;
  for (int m = 32; m; m >>= 1) {
    s1 += __shfl_xor(s1, m, 64);
    s2 += __shfl_xor(s2, m, 64);
  }
  if (lane == 0) {
    const float mu = s1 * (1.0f / 40.0f);
    const float var = s2 * (1.0f / 40.0f) - mu * mu;
    mu_arr[row] = mu;
    rs_arr[row] = rsqrtf(var + 1e-5f);
  }
}

// ---------------- xw0 chunk = LN(x)[slice] @ Wih0^T  (LN fused into A-load) ----------------
__global__ __launch_bounds__(256, 2) void gemm_xw0(
    const float* __restrict__ x,
    const float* __restrict__ mu_arr, const float* __restrict__ rs_arr,
    const float* __restrict__ ln_g, const float* __restrict__ ln_b,
    const float* __restrict__ Wf, const float* __restrict__ Wb,
    float* __restrict__ xwf, float* __restrict__ xwb,
    int Tc, int t0f, int t0b) {
  __shared__ float As[64 * 44];   // 64 rows x 11 float4 (10 data + 1 pad)
  __shared__ float Bs[128 * 44];
  const int tid = threadIdx.x;
  const int tx = tid & 15, ty = tid >> 4;
  const int r0 = blockIdx.x * 64;
  const int jt = blockIdx.y;
  const int dir = jt >> 2, nh = jt & 3;
  const float* __restrict__ W = dir ? Wb : Wf;
  float* __restrict__ out = dir ? xwb : xwf;
  const int jbase = nh * 128;
  const int t0 = dir ? t0b : t0f;

  float4* As4 = (float4*)As;
  float4* Bs4 = (float4*)Bs;
  {  // A stage with fused LayerNorm: 4 threads per row
    const int row = tid >> 2;
    const int t4 = tid & 3;
    const int r = r0 + row;
    const int br = r / Tc;
    const long xrow = (long)br * T_ + t0 + (r - br * Tc);
    const float mu = mu_arr[xrow];
    const float rs = rs_arr[xrow];
#pragma unroll
    for (int m = 0; m < 3; ++m) {
      const int k4 = t4 + m * 4;
      if (k4 < 10) {
        const float4 v = *(const float4*)&x[xrow * 40 + k4 * 4];
        const float4 g4 = *(const float4*)&ln_g[k4 * 4];
        const float4 b4 = *(const float4*)&ln_b[k4 * 4];
        float4 xn;
        xn.x = (v.x - mu) * rs * g4.x + b4.x;
        xn.y = (v.y - mu) * rs * g4.y + b4.y;
        xn.z = (v.z - mu) * rs * g4.z + b4.z;
        xn.w = (v.w - mu) * rs * g4.w + b4.w;
        As4[row * 11 + k4] = xn;
      }
    }
  }
  {  // B stage: 2 threads per row
    const int row = tid & 127;
    const int h = tid >> 7;
#pragma unroll
    for (int m = 0; m < 5; ++m) {
      const int k4 = h + m * 2;
      Bs4[row * 11 + k4] = *(const float4*)&W[(long)(jbase + row) * 40 + k4 * 4];
    }
  }
  __syncthreads();

  v2f acc2[4][8];
#pragma unroll
  for (int r = 0; r < 4; ++r)
#pragma unroll
    for (int c2 = 0; c2 < 8; ++c2) acc2[r][c2] = 0.0f;
#pragma unroll 1
  for (int k4 = 0; k4 < 10; ++k4) {
    float4 av[4];
#pragma unroll
    for (int r = 0; r < 4; ++r) av[r] = As4[(ty * 4 + r) * 11 + k4];
#pragma unroll
    for (int c2 = 0; c2 < 8; ++c2) {
      const float4 bv = Bs4[(tx + 16 * c2) * 11 + k4];
#pragma unroll
      for (int r = 0; r < 4; ++r) pkfma(acc2[r][c2], av[r], bv);
    }
  }
#pragma unroll
  for (int r = 0; r < 4; ++r) {
    const long ob = (long)(r0 + ty * 4 + r) * 512 + jbase + tx;
#pragma unroll
    for (int c2 = 0; c2 < 8; ++c2) out[ob + c2 * 16] = acc2[r][c2][0] + acc2[r][c2][1];
  }
}

// ---------------- Unified recurrence: quad-split, ALL 4 gates' Whh as f16 pairs in REGISTERS ----------------
// lane: unit u = wave*16 + (lane>>2), k-quarter p = lane&3.
// Weight footprint: 4 gates x 16 h2t = 64 VGPRs + ~45 working < 128-VGPR cap of 512-thr
// blocks -> no AGPR spill movs (r7-r10) and no LDS weight streaming (r11's 4.1M bank
// conflicts + 375cy/step LDS floor). Dot via v_dot2_f32_f16 (2 MACs/inst, full rate).
// h4f parity double-buffer: read su&1, write (su&1)^1; 1 barrier/step.
__global__ __launch_bounds__(512) void rec_fused(
    const float* __restrict__ xw_f, const float* __restrict__ xw_b,
    const float* __restrict__ Whh_f, const float* __restrict__ Whh_b,
    const float* __restrict__ bih_f, const float* __restrict__ bhh_f,
    const float* __restrict__ bih_b, const float* __restrict__ bhh_b,
    float* __restrict__ h0out, unsigned short* __restrict__ h1out, int out_bf16,
    float* __restrict__ state, int Tc, int t0f, int t0b, int first) {
  const int tid = threadIdx.x;
  const int u = (tid >> 6) * 16 + ((tid & 63) >> 2);
  const int p = tid & 3;
  const int brow = blockIdx.x & 127;
  const int dir = blockIdx.x >> 7;
  const float* __restrict__ xw  = dir ? xw_b : xw_f;
  const float* __restrict__ Whh = dir ? Whh_b : Whh_f;
  const float* __restrict__ bih = dir ? bih_b : bih_f;
  const float* __restrict__ bhh = dir ? bhh_b : bhh_f;
  const int t0 = dir ? t0b : t0f;

  // f16-pair register weights, chunk-rotated: whp[g][2ff],[2ff+1] covers global k-chunk
  // c8=(ff+2p)&7 of this lane's quarter (pairs with h4v[p*8+c8] at step time).
  h2t whp[4][16];
#pragma unroll
  for (int g = 0; g < 4; ++g) {
    const float4* wr = (const float4*)(Whh + (g * 128 + u) * 128 + p * 32);
#pragma unroll
    for (int ff = 0; ff < 8; ++ff) {
      const float4 w4 = wr[(ff + 2 * p) & 7];
      h2t lo; lo[0] = (__fp16)w4.x; lo[1] = (__fp16)w4.y;
      h2t hi; hi[0] = (__fp16)w4.z; hi[1] = (__fp16)w4.w;
      whp[g][2 * ff] = lo;
      whp[g][2 * ff + 1] = hi;
    }
  }
  const int myrow = p * 128 + u;
  const float bias_p = bih[myrow] + bhh[myrow];

  __shared__ float h4f[2][128];
  __shared__ float hring[2][8][128];
  float* sblk = state + (long)blockIdx.x * 256;
  float c = 0.0f;
  if (first) {
    if (tid < 128) h4f[0][tid] = 0.0f;
  } else {
    if (tid < 128) h4f[0][tid] = sblk[tid];
    c = sblk[128 + u];  // replicated per quad
  }
  const long gbase = (long)brow * Tc;
  float xr[8];
#pragma unroll
  for (int v = 0; v < 8; ++v) {
    xr[v] = 0.0f;
    if (v < Tc) {
      const int tr = dir ? (Tc - 1 - v) : v;
      xr[v] = xw[(gbase + tr) * 512 + myrow];
    }
  }
  __syncthreads();

  const int nSB = (Tc + 7) / 8;
  const long obase = (long)brow * T_;
  for (int sb = 0; sb < nSB; ++sb) {
    const int rb = sb & 1;
#pragma unroll
    for (int su = 0; su < 8; ++su) {
      const int s = sb * 8 + su;
      if (s >= Tc) break;  // uniform
      const int rdq = su & 1, wrq = rdq ^ 1;
      if (su == 0 && sb > 0) {  // bulk store of previous (full) group
#pragma unroll
        for (int e = 0; e < 2; ++e) {
          const int idx = tid + e * 512;
          const int v = idx >> 7, j = idx & 127;
          const int s2 = (sb - 1) * 8 + v;
          const int tt = dir ? (Tc - 1 - s2) : s2;
          const long oidx = (obase + (t0 + tt)) * 256 + dir * 128 + j;
          const float hval = hring[rb ^ 1][v][j];
          if (out_bf16) h1out[oidx] = f2bf(hval);
          else          h0out[oidx] = hval;
        }
      }
      // ---- dot phase: 8 broadcast LDS reads + 16 cvt + 64 dot2 ----
      float a0 = 0.f, a1 = 0.f, a2 = 0.f, a3 = 0.f;
      const float4* h4v = (const float4*)h4f[rdq];
#pragma unroll
      for (int ff = 0; ff < 8; ++ff) {
        const float4 hv = h4v[p * 8 + ((ff + 2 * p) & 7)];
#if HAS_FDOT2
        const h2t hp0 = __builtin_amdgcn_cvt_pkrtz(hv.x, hv.y);
        const h2t hp1 = __builtin_amdgcn_cvt_pkrtz(hv.z, hv.w);
        a0 = __builtin_amdgcn_fdot2(hp0, whp[0][2 * ff], a0, false);
        a0 = __builtin_amdgcn_fdot2(hp1, whp[0][2 * ff + 1], a0, false);
        a1 = __builtin_amdgcn_fdot2(hp0, whp[1][2 * ff], a1, false);
        a1 = __builtin_amdgcn_fdot2(hp1, whp[1][2 * ff + 1], a1, false);
        a2 = __builtin_amdgcn_fdot2(hp0, whp[2][2 * ff], a2, false);
        a2 = __builtin_amdgcn_fdot2(hp1, whp[2][2 * ff + 1], a2, false);
        a3 = __builtin_amdgcn_fdot2(hp0, whp[3][2 * ff], a3, false);
        a3 = __builtin_amdgcn_fdot2(hp1, whp[3][2 * ff + 1], a3, false);
#else
        // fma-mix fallback: f16 weight operand mixed with f32 h (correct either way).
        a0 = fmaf((float)whp[0][2 * ff][0], hv.x, a0);
        a0 = fmaf((float)whp[0][2 * ff][1], hv.y, a0);
        a0 = fmaf((float)whp[0][2 * ff + 1][0], hv.z, a0);
        a0 = fmaf((float)whp[0][2 * ff + 1][1], hv.w, a0);
        a1 = fmaf((float)whp[1][2 * ff][0], hv.x, a1);
        a1 = fmaf((float)whp[1][2 * ff][1], hv.y, a1);
        a1 = fmaf((float)whp[1][2 * ff + 1][0], hv.z, a1);
        a1 = fmaf((float)whp[1][2 * ff + 1][1], hv.w, a1);
        a2 = fmaf((float)whp[2][2 * ff][0], hv.x, a2);
        a2 = fmaf((float)whp[2][2 * ff][1], hv.y, a2);
        a2 = fmaf((float)whp[2][2 * ff + 1][0], hv.z, a2);
        a2 = fmaf((float)whp[2][2 * ff + 1][1], hv.w, a2);
        a3 = fmaf((float)whp[3][2 * ff][0], hv.x, a3);
        a3 = fmaf((float)whp[3][2 * ff][1], hv.y, a3);
        a3 = fmaf((float)whp[3][2 * ff + 1][0], hv.z, a3);
        a3 = fmaf((float)whp[3][2 * ff + 1][1], hv.w, a3);
#endif
      }
      const float xin = xr[su] + bias_p;
      float pg0 = a0 + ((p == 0) ? xin : 0.0f);
      float pg1 = a1 + ((p == 1) ? xin : 0.0f);
      float pg2 = a2 + ((p == 2) ? xin : 0.0f);
      float pg3 = a3 + ((p == 3) ? xin : 0.0f);
      pg0 += __shfl_xor(pg0, 1, 64); pg0 += __shfl_xor(pg0, 2, 64);
      pg1 += __shfl_xor(pg1, 1, 64); pg1 += __shfl_xor(pg1, 2, 64);
      pg2 += __shfl_xor(pg2, 1, 64); pg2 += __shfl_xor(pg2, 2, 64);
      pg3 += __shfl_xor(pg3, 1, 64); pg3 += __shfl_xor(pg3, 2, 64);
      const float ig = sigf(pg0);
      const float fg = sigf(pg1);
      const float gg = tanh_fast(pg2);
      const float og = sigf(pg3);
      c = fg * c + ig * gg;
      const float hv2 = og * tanh_fast(c);
      if (p == 0) { h4f[wrq][u] = hv2; hring[rb][su][u] = hv2; }
      if (su == 7) {  // refill xw for next group
#pragma unroll
        for (int v = 0; v < 8; ++v) {
          const int sn = s + 1 + v;
          xr[v] = 0.0f;
          if (sn < Tc) {
            const int tr = dir ? (Tc - 1 - sn) : sn;
            xr[v] = xw[(gbase + tr) * 512 + myrow];
          }
        }
      }
      __syncthreads();
    }
  }
  {  // final (possibly partial) group store
    const int sbL = (Tc - 1) >> 3;
    const int cnt = Tc - sbL * 8;
    const int rbL = sbL & 1;
#pragma unroll
    for (int e = 0; e < 2; ++e) {
      const int idx = tid + e * 512;
      const int v = idx >> 7, j = idx & 127;
      if (v < cnt) {
        const int s2 = sbL * 8 + v;
        const int tt = dir ? (Tc - 1 - s2) : s2;
        const long oidx = (obase + (t0 + tt)) * 256 + dir * 128 + j;
        const float hval = hring[rbL][v][j];
        if (out_bf16) h1out[oidx] = f2bf(hval);
        else          h0out[oidx] = hval;
      }
    }
  }
  if (tid < 128) sblk[tid] = h4f[Tc & 1][tid];
  if (p == 0) sblk[128 + u] = c;
}

// ---------------- xw1 chunk GEMM: tile M=64 x N=128, K=256, micro 4x8, pk acc ----------------
__global__ __launch_bounds__(256, 2) void gemm_xw1(
    const float* __restrict__ h0,
    const float* __restrict__ Wf, const float* __restrict__ Wb,
    float* __restrict__ xwf, float* __restrict__ xwb,
    int Tc, int t0f, int t0b) {
  __shared__ float As[64 * 36];
  __shared__ float Bs[128 * 36];
  __shared__ int rowbase[64];
  const int tid = threadIdx.x;
  const int tx = tid & 15, ty = tid >> 4;
  const int r0 = blockIdx.x * 64;
  const int jt = blockIdx.y;
  const int dir = jt >> 2;
  const int nh = jt & 3;
  const float* __restrict__ W = dir ? Wb : Wf;
  float* __restrict__ out = dir ? xwb : xwf;
  const int jbase = nh * 128;
  const int t0 = dir ? t0b : t0f;

  if (tid < 64) {
    const int r = r0 + tid;
    const int br = r / Tc;
    rowbase[tid] = br * T_ + t0 + (r - br * Tc);
  }

  float4* As4 = (float4*)As;
  float4* Bs4 = (float4*)Bs;
  v2f acc2[4][8];
#pragma unroll
  for (int r = 0; r < 4; ++r)
#pragma unroll
    for (int c2 = 0; c2 < 8; ++c2) acc2[r][c2] = 0.0f;
#pragma unroll 1
  for (int kk = 0; kk < 8; ++kk) {
    __syncthreads();
#pragma unroll
    for (int i = 0; i < 2; ++i) {
      const int q = tid + i * 256;
      const int row = q >> 3, k4 = q & 7;
      As4[row * 9 + k4] = *(const float4*)&h0[(long)rowbase[row] * 256 + kk * 32 + k4 * 4];
    }
#pragma unroll
    for (int i = 0; i < 4; ++i) {
      const int q = tid + i * 256;
      const int row = q >> 3, k4 = q & 7;
      Bs4[row * 9 + k4] = *(const float4*)&W[(long)(jbase + row) * 256 + kk * 32 + k4 * 4];
    }
    __syncthreads();
#pragma unroll 1
    for (int k4 = 0; k4 < 8; ++k4) {
      float4 av[4];
#pragma unroll
      for (int r = 0; r < 4; ++r) av[r] = As4[(ty * 4 + r) * 9 + k4];
#pragma unroll
      for (int c2 = 0; c2 < 8; ++c2) {
        const float4 bv = Bs4[(tx + 16 * c2) * 9 + k4];
#pragma unroll
        for (int r = 0; r < 4; ++r) pkfma(acc2[r][c2], av[r], bv);
      }
    }
  }
#pragma unroll
  for (int r = 0; r < 4; ++r) {
    const long ob = (long)(r0 + ty * 4 + r) * 512 + jbase + tx;
#pragma unroll
    for (int c2 = 0; c2 < 8; ++c2) out[ob + c2 * 16] = acc2[r][c2][0] + acc2[r][c2][1];
  }
}

// ---------------- attention scores ----------------
__global__ __launch_bounds__(256, 2) void score_kernel(
    const unsigned short* __restrict__ h1b, const float* __restrict__ W1,
    const float* __restrict__ b1, const float* __restrict__ w2,
    float* __restrict__ scores) {
  __shared__ float As[64 * 36];
  __shared__ float Bs[128 * 36];
  const int tid = threadIdx.x;
  const int tx = tid & 15, ty = tid >> 4;
  const long r0 = (long)blockIdx.x * 64;

  float4* As4 = (float4*)As;
  float4* Bs4 = (float4*)Bs;
  v2f acc2[4][8];
#pragma unroll
  for (int r = 0; r < 4; ++r)
#pragma unroll
    for (int c2 = 0; c2 < 8; ++c2) acc2[r][c2] = 0.0f;
#pragma unroll 1
  for (int kk = 0; kk < 8; ++kk) {
    __syncthreads();
#pragma unroll
    for (int i = 0; i < 2; ++i) {
      const int q = tid + i * 256;
      const int row = q >> 3, k4 = q & 7;
      const ushort4 uv = *(const ushort4*)&h1b[(r0 + row) * 256 + kk * 32 + k4 * 4];
      As4[row * 9 + k4] = bf4_to_f4(uv);
    }
#pragma unroll
    for (int i = 0; i < 4; ++i) {
      const int q = tid + i * 256;
      const int row = q >> 3, k4 = q & 7;
      Bs4[row * 9 + k4] = *(const float4*)&W1[(long)row * 256 + kk * 32 + k4 * 4];
    }
    __syncthreads();
#pragma unroll 1
    for (int k4 = 0; k4 < 8; ++k4) {
      float4 av[4];
#pragma unroll
      for (int r = 0; r < 4; ++r) av[r] = As4[(ty * 4 + r) * 9 + k4];
#pragma unroll
      for (int c2 = 0; c2 < 8; ++c2) {
        const float4 bv = Bs4[(tx + 16 * c2) * 9 + k4];
#pragma unroll
        for (int r = 0; r < 4; ++r) pkfma(acc2[r][c2], av[r], bv);
      }
    }
  }
#pragma unroll
  for (int r = 0; r < 4; ++r) {
    float s = 0.0f;
#pragma unroll
    for (int c2 = 0; c2 < 8; ++c2) {
      const int col = tx + 16 * c2;
      s += tanh_fast(acc2[r][c2][0] + acc2[r][c2][1] + b1[col]) * w2[col];
    }
#pragma unroll
    for (int m = 1; m < 16; m <<= 1) s += __shfl_xor(s, m, 16);
    if (tx == 0) scores[r0 + ty * 4 + r] = s;
  }
}

// ---------------- softmax over T + ctx + MLP head ----------------
__global__ __launch_bounds__(256, 2) void head_kernel(
    const float* __restrict__ scores, const unsigned short* __restrict__ h1b,
    const float* __restrict__ fW1, const float* __restrict__ fb1,
    const float* __restrict__ fW2, const float* __restrict__ fb2,
    float* __restrict__ outp) {
  const int b = blockIdx.x, tid = threadIdx.x;
  __shared__ float wls[1000];
  __shared__ float red[8];
  __shared__ __align__(16) float ctx[256];
  __shared__ __align__(16) float hid[128];

  float sv[4];
  float mx = -1e30f;
#pragma unroll
  for (int i = 0; i < 4; ++i) {
    const int t = tid + i * 256;
    sv[i] = (t < 1000) ? scores[b * 1000 + t] : -1e30f;
    mx = fmaxf(mx, sv[i]);
  }
  for (int m = 32; m; m >>= 1) mx = fmaxf(mx, __shfl_xor(mx, m, 64));
  if ((tid & 63) == 0) red[tid >> 6] = mx;
  __syncthreads();
  mx = fmaxf(fmaxf(red[0], red[1]), fmaxf(red[2], red[3]));
  float se = 0.0f;
#pragma unroll
  for (int i = 0; i < 4; ++i) {
    const int t = tid + i * 256;
    if (t < 1000) {
      const float e = __expf(sv[i] - mx);
      wls[t] = e;
      se += e;
    }
  }
  for (int m = 32; m; m >>= 1) se += __shfl_xor(se, m, 64);
  if ((tid & 63) == 0) red[4 + (tid >> 6)] = se;
  __syncthreads();
  const float rinv = 1.0f / (red[4] + red[5] + red[6] + red[7]);

  float a = 0.0f;
  const unsigned short* hb = h1b + (long)b * T_ * 256 + tid;
  for (int t = 0; t < T_; ++t) a = fmaf(wls[t], bf2f(hb[t * 256]), a);
  ctx[tid] = a * rinv;
  __syncthreads();
  if (tid < 128) {
    float s = fb1[tid];
    const float4* wr = (const float4*)&fW1[tid * 256];
    const float4* cc = (const float4*)ctx;
#pragma unroll
    for (int f = 0; f < 64; ++f) s += dot4(wr[f], cc[f]);
    hid[tid] = fmaxf(s, 0.0f);
  }
  __syncthreads();
  if (tid < 8) {
    float s = fb2[tid];
    const float4* wr = (const float4*)&fW2[tid * 128];
    const float4* hh = (const float4*)hid;
#pragma unroll
    for (int f = 0; f < 32; ++f) s += dot4(wr[f], hh[f]);
    outp[b * 8 + tid] = s;
  }
}

extern "C" void kernel_launch(void* const* d_in, const int* in_sizes, int n_in,
                              void* d_out, int out_size, void* d_ws, size_t ws_size,
                              hipStream_t stream) {
  (void)in_sizes; (void)n_in; (void)out_size;
  const float* x       = (const float*)d_in[0];
  const float* ln_g    = (const float*)d_in[1];
  const float* ln_b    = (const float*)d_in[2];
  const float* Wih_f0  = (const float*)d_in[3];
  const float* Whh_f0  = (const float*)d_in[4];
  const float* bih_f0  = (const float*)d_in[5];
  const float* bhh_f0  = (const float*)d_in[6];
  const float* Wih_b0  = (const float*)d_in[7];
  const float* Whh_b0  = (const float*)d_in[8];
  const float* bih_b0  = (const float*)d_in[9];
  const float* bhh_b0  = (const float*)d_in[10];
  const float* Wih_f1  = (const float*)d_in[11];
  const float* Whh_f1  = (const float*)d_in[12];
  const float* bih_f1  = (const float*)d_in[13];
  const float* bhh_f1  = (const float*)d_in[14];
  const float* Wih_b1  = (const float*)d_in[15];
  const float* Whh_b1  = (const float*)d_in[16];
  const float* bih_b1  = (const float*)d_in[17];
  const float* bhh_b1  = (const float*)d_in[18];
  const float* attn_W1 = (const float*)d_in[19];
  const float* attn_b1 = (const float*)d_in[20];
  const float* attn_w2 = (const float*)d_in[21];
  const float* fc_W1   = (const float*)d_in[22];
  const float* fc_b1   = (const float*)d_in[23];
  const float* fc_W2   = (const float*)d_in[24];
  const float* fc_b2   = (const float*)d_in[25];

  char* base = (char*)d_ws;
  size_t off = 0;
  auto alloc = [&](size_t bytes) {
    char* ptr = base + off;
    off += (bytes + 255) & ~(size_t)255;
    return ptr;
  };
  float*          h0    = (float*)alloc(32768000ull * 4);          // 131.1 MB
  unsigned short* h1b   = (unsigned short*)alloc(32768000ull * 2); //  65.5 MB
  float*          state = (float*)alloc(65536ull * 4);
  float*          scor  = (float*)alloc(128000ull * 4);
  float*          mu_a  = (float*)alloc(128000ull * 4);
  float*          rs_a  = (float*)alloc(128000ull * 4);

  const size_t rem = (ws_size > off) ? (ws_size - off) : 0;
  static const int cands[16] = {1000, 500, 250, 200, 125, 100, 50, 40, 25, 20, 10, 8, 5, 4, 2, 1};
  int Tc = 0;
  for (int ci = 0; ci < 16; ++ci) {
    if (524288ull * (size_t)cands[ci] <= rem) { Tc = cands[ci]; break; }
  }
  if (Tc == 0) {
    bail_kernel<<<dim3(1), dim3(256), 0, stream>>>((float*)d_out, 1024);
    return;
  }
  float* xwf = (float*)(base + off);
  float* xwb = xwf + 65536L * Tc;

  ln_stats_kernel<<<dim3(32000), dim3(256), 0, stream>>>(x, mu_a, rs_a);
  const int nch = T_ / Tc;
  // Layer 0: xw0 chunk GEMM (LN fused) + recurrence
  for (int ch = 0; ch < nch; ++ch) {
    const int t0f = ch * Tc;
    const int t0b = T_ - (ch + 1) * Tc;
    gemm_xw0<<<dim3(2 * Tc, 8), dim3(256), 0, stream>>>(x, mu_a, rs_a, ln_g, ln_b,
                                                        Wih_f0, Wih_b0, xwf, xwb, Tc, t0f, t0b);
    rec_fused<<<dim3(256), dim3(512), 0, stream>>>(xwf, xwb, Whh_f0, Whh_b0,
                                                   bih_f0, bhh_f0, bih_b0, bhh_b0,
                                                   h0, h1b, 0, state, Tc, t0f, t0b,
                                                   (ch == 0) ? 1 : 0);
  }
  // Layer 1: xw1 chunk GEMM + recurrence (bf16 h1 out)
  for (int ch = 0; ch < nch; ++ch) {
    const int t0f = ch * Tc;
    const int t0b = T_ - (ch + 1) * Tc;
    gemm_xw1<<<dim3(2 * Tc, 8), dim3(256), 0, stream>>>(h0, Wih_f1, Wih_b1, xwf, xwb, Tc, t0f, t0b);
    rec_fused<<<dim3(256), dim3(512), 0, stream>>>(xwf, xwb, Whh_f1, Whh_b1,
                                                   bih_f1, bhh_f1, bih_b1, bhh_b1,
                                                   h0, h1b, 1, state, Tc, t0f, t0b,
                                                   (ch == 0) ? 1 : 0);
  }
  score_kernel<<<dim3(2000), dim3(256), 0, stream>>>(h1b, attn_W1, attn_b1, attn_w2, scor);
  head_kernel<<<dim3(128), dim3(256), 0, stream>>>(scor, h1b, fc_W1, fc_b1, fc_W2, fc_b2,
                                                   (float*)d_out);
}